// Round 2
// baseline (635.097 us; speedup 1.0000x reference)
//
#include <hip/hip_runtime.h>
#include <math.h>

// Problem constants
#define HO 512
#define WO 512
#define HI 128
#define WI 128
#define CC 64      // channels
#define BS 2       // batch
#define NPX 64     // pixels per block (one row segment)
#define NT 256     // threads per block

// d_ws layout:
//   [0)              bf16 packed weights: w2p then w3p
//   [XT_BYTE_OFF)    x_t padded transpose: float [130][130][64][2]  (c-major, b innermost)
#define W2P_ELEMS (16 * 2 * 64 * 8)      // [nt=16][ks=2][lane=64][j=8]
#define W3P_ELEMS (36 * 8 * 64 * 8)      // [nt=36][ks=8][lane=64][j=8], nt = tap*4+chtile
#define XT_ELEM_OFF (W2P_ELEMS + W3P_ELEMS)     // in shorts (163840 -> 327680 B, 16B aligned)
#define XT_FLOATS (130 * 130 * 128)             // 2,163,200 floats = 8.65 MB

typedef __attribute__((ext_vector_type(8))) short short8;
typedef __attribute__((ext_vector_type(4))) float float4v;
typedef __attribute__((ext_vector_type(2))) float float2v;

__device__ __forceinline__ unsigned short f2bf(float f) {
    unsigned u = __builtin_bit_cast(unsigned, f);
    unsigned r = (u + 0x7FFFu + ((u >> 16) & 1u)) >> 16;   // RNE
    return (unsigned short)r;
}

// ---------------- k1: pack weights to MFMA-B order + zero x_t ----------------
// B-frag (16x16x32): lane l holds B[n=l&15][k=(l>>4)*8+j], j=0..7
// W3 n-tile nt = tap*4 + chtile: covers W3 rows (chtile*16 + (l&15))*9 + tap
__global__ void prepack_zw(const float* __restrict__ W2,
                           const float* __restrict__ W3,
                           unsigned short* __restrict__ wsp,
                           float* __restrict__ xt) {
    const int total = W2P_ELEMS + W3P_ELEMS;
    for (int idx = blockIdx.x * blockDim.x + threadIdx.x; idx < total;
         idx += gridDim.x * blockDim.x) {
        float v;
        if (idx < W2P_ELEMS) {
            int j = idx & 7, lane = (idx >> 3) & 63, rest = idx >> 9;
            int ks = rest & 1, nt = rest >> 1;
            int n = nt * 16 + (lane & 15);
            int k = ks * 32 + (lane >> 4) * 8 + j;
            v = W2[n * 64 + k];                      // W2: [256][64]
        } else {
            int i2 = idx - W2P_ELEMS;
            int j = i2 & 7, lane = (i2 >> 3) & 63, rest = i2 >> 9;
            int ks = rest & 7, nt = rest >> 3;       // nt = tap*4+chtile
            int tap = nt >> 2, ct = nt & 3;
            int row = (ct * 16 + (lane & 15)) * 9 + tap;   // < 576
            int k = ks * 32 + (lane >> 4) * 8 + j;
            v = W3[row * 256 + k];                   // W3: [576][256]
        }
        wsp[idx] = f2bf(v);
    }
    // zero x_t (borders stay zero; interior overwritten by prepack_x)
    float4v z = {0.f, 0.f, 0.f, 0.f};
    float4v* xt4 = (float4v*)xt;
    for (int i = blockIdx.x * blockDim.x + threadIdx.x; i < XT_FLOATS / 4;
         i += gridDim.x * blockDim.x)
        xt4[i] = z;
}

// ---------------- k2: x -> x_t[(h+1)][(w+1)][c][b] (interior) ----------------
// 262144 threads; lanes consecutive = consecutive w -> coalesced reads.
// Batch innermost: gather in fused_main becomes one float2 per (tap, channel).
__global__ void prepack_x(const float* __restrict__ x, float* __restrict__ xt) {
    const int tid = blockIdx.x * blockDim.x + threadIdx.x;
    const int pos = tid & 16383;          // h*128+w
    const int g   = tid >> 14;            // channel group: 4 channels x 2 batches
    const int h = pos >> 7, w = pos & 127;
    const float* src = x + pos;
    float a0[4], a1[4];
    #pragma unroll
    for (int j = 0; j < 4; ++j) a0[j] = src[(size_t)(g * 4 + j) * (HI * WI)];            // b=0
    #pragma unroll
    for (int j = 0; j < 4; ++j) a1[j] = src[(size_t)(CC + g * 4 + j) * (HI * WI)];       // b=1
    float* dst = xt + ((h + 1) * 130 + (w + 1)) * 128 + g * 8;
    *(float4v*)dst       = (float4v){a0[0], a1[0], a0[1], a1[1]};
    *(float4v*)(dst + 4) = (float4v){a0[2], a1[2], a0[3], a1[3]};
}

// ---------------- fused main kernel ----------------
// Per block: 64 pixels (one row segment), 4 waves x 16 pixels.
// stage1 (VALU): h1[64][64] -> LDS bf16
// stage2 (MFMA): h2[64][256] -> LDS bf16
// stage3 (MFMA): per chtile (16 ch): PREFETCH the 36 float2 gathers for this ct
//                BEFORE the MFMA b-frag stream (in-order vmcnt: one bounded
//                drain at the first MFMA instead of 4 exposed per-r stalls),
//                then 9 tap-logits in registers -> softmax in regs -> sOut
//                transpose -> coalesced full-line stores (proven 303us path).
__global__ __launch_bounds__(NT, 3)
void fused_main(const float* __restrict__ xt, const float* __restrict__ pose,
                const float* __restrict__ W1, const float* __restrict__ b1,
                const float* __restrict__ b2, const float* __restrict__ b3,
                const int* __restrict__ iY, const int* __restrict__ iX,
                const unsigned short* __restrict__ wsp,
                float* __restrict__ out)
{
    // Manual LDS layout (52.5 KB -> 3 blocks/CU). sH1 dead after stage2;
    // overlap it with the double-buffered sOut transpose tile.
    __shared__ char smem[33792 + 17408 + 768 + 512];
    unsigned short (*sH2)[264] = (unsigned short (*)[264])&smem[0];        // 33792 B
    unsigned short (*sH1)[72]  = (unsigned short (*)[72])&smem[33792];     // 9216 B (union)
    float (*sOut)[2][16][68]   = (float (*)[2][16][68])&smem[33792];       // 2x8704 B (union)
    float (*sP)[NPX]           = (float (*)[NPX])&smem[51200];             // 768 B
    int* sIY                   = (int*)&smem[51968];                       // 256 B
    int* sIX                   = (int*)&smem[52224];                       // 256 B

    const int t = threadIdx.x;
    const int pixBase = blockIdx.x * NPX;    // 64 px within one output row
    const int y  = pixBase / WO;
    const int x0 = pixBase % WO;

    if (t < 192) sP[t >> 6][t & 63] = pose[(t >> 6) * (HO * WO) + pixBase + (t & 63)];
    if (t < 64) sIY[t] = iY[pixBase + t];
    else if (t < 128) sIX[t - 64] = iX[pixBase + t - 64];
    __syncthreads();

    // ---- stage 1: h1 = relu(W1 @ p + b1)
    {
        const int p  = t & 63;
        const int og = t >> 6;
        const float p0 = sP[0][p], p1 = sP[1][p], p2 = sP[2][p];
        #pragma unroll
        for (int i = 0; i < 16; i += 2) {
            const int o = og * 16 + i;
            float a0 = fmaf(W1[o * 3 + 2], p2, fmaf(W1[o * 3 + 1], p1, fmaf(W1[o * 3 + 0], p0, b1[o])));
            float a1 = fmaf(W1[o * 3 + 5], p2, fmaf(W1[o * 3 + 4], p1, fmaf(W1[o * 3 + 3], p0, b1[o + 1])));
            a0 = fmaxf(a0, 0.f); a1 = fmaxf(a1, 0.f);
            unsigned pack = (unsigned)f2bf(a0) | ((unsigned)f2bf(a1) << 16);
            *(unsigned*)&sH1[p][o] = pack;
        }
    }
    __syncthreads();

    const int wv = t >> 6, l = t & 63, lm = l & 15, lq = l >> 4;
    const int m0 = wv * 16;                  // wave's pixel base

    // ---- stage 2: h2 = relu(h1 @ W2^T + b2)  [16px x 256] per wave
    {
        short8 a0 = *(const short8*)&sH1[m0 + lm][0  + lq * 8];
        short8 a1 = *(const short8*)&sH1[m0 + lm][32 + lq * 8];
        const short8* w2f = (const short8*)wsp;
        #pragma unroll 4
        for (int nt = 0; nt < 16; ++nt) {
            float4v acc = {0.f, 0.f, 0.f, 0.f};
            short8 bf0 = w2f[(nt * 2 + 0) * 64 + l];
            short8 bf1 = w2f[(nt * 2 + 1) * 64 + l];
            acc = __builtin_amdgcn_mfma_f32_16x16x32_bf16(a0, bf0, acc, 0, 0, 0);
            acc = __builtin_amdgcn_mfma_f32_16x16x32_bf16(a1, bf1, acc, 0, 0, 0);
            const float bv = b2[nt * 16 + lm];
            #pragma unroll
            for (int r = 0; r < 4; ++r)
                sH2[m0 + lq * 4 + r][nt * 16 + lm] = f2bf(fmaxf(acc[r] + bv, 0.f));
        }
    }
    __syncthreads();   // sH1 also dead beyond this point (sOut may overwrite)

    // per-lane pixel bases into x_t (pixels p = m0 + lq*4 + r)
    int pbase[4];
    #pragma unroll
    for (int r = 0; r < 4; ++r) {
        const int p = m0 + lq * 4 + r;
        pbase[r] = ((sIY[p] + 1) * 130 + (sIX[p] + 1)) * 128;
    }
    const int koff[9] = {-131 * 128, -130 * 128, -129 * 128,
                         -1 * 128,   0,          1 * 128,
                         129 * 128,  130 * 128,  131 * 128};
    const short8* w3f = (const short8*)(wsp + W2P_ELEMS);

    // ---- stage 3: 4 chtiles of 16 channels; 9 taps in registers
    for (int ct = 0; ct < 4; ++ct) {
        const int c = ct * 16 + lm;          // this lane's channel

        // PREFETCH: issue all 36 float2 gathers for this ct up front.
        // 16 lm-lanes x 8B = one contiguous 128B segment per (lq, tap).
        // In-order vmcnt drains these once, under the MFMA b-frag stream.
        float2v g[4][9];
        #pragma unroll
        for (int r = 0; r < 4; ++r) {
            const float* xb = xt + pbase[r] + 2 * c;
            #pragma unroll
            for (int tap = 0; tap < 9; ++tap)
                g[r][tap] = *(const float2v*)(xb + koff[tap]);
        }

        float4v accs[9];
        #pragma unroll
        for (int tap = 0; tap < 9; ++tap) accs[tap] = (float4v){0.f, 0.f, 0.f, 0.f};

        #pragma unroll 2
        for (int ks = 0; ks < 8; ++ks) {
            short8 a = *(const short8*)&sH2[m0 + lm][ks * 32 + lq * 8];
            #pragma unroll
            for (int tap = 0; tap < 9; ++tap) {
                short8 b = w3f[(((tap << 2) | ct) * 8 + ks) * 64 + l];
                accs[tap] = __builtin_amdgcn_mfma_f32_16x16x32_bf16(a, b, accs[tap], 0, 0, 0);
            }
        }

        float bv[9];
        #pragma unroll
        for (int tap = 0; tap < 9; ++tap) bv[tap] = b3[c * 9 + tap];

        float ob0[4], ob1[4];
        #pragma unroll
        for (int r = 0; r < 4; ++r) {
            float lg[9];
            #pragma unroll
            for (int tap = 0; tap < 9; ++tap) lg[tap] = accs[tap][r] + bv[tap];
            float mx = lg[0];
            #pragma unroll
            for (int tap = 1; tap < 9; ++tap) mx = fmaxf(mx, lg[tap]);
            float s = 0.f, o0 = 0.f, o1 = 0.f;
            #pragma unroll
            for (int tap = 0; tap < 9; ++tap) {
                const float ev = __expf(lg[tap] - mx);
                s += ev;
                o0 = fmaf(ev, g[r][tap][0], o0);     // b=0 (prefetched)
                o1 = fmaf(ev, g[r][tap][1], o1);     // b=1 (prefetched)
            }
            const float inv = 1.f / s;
            ob0[r] = o0 * inv;
            ob1[r] = o1 * inv;
        }

        // transpose via LDS (double-buffered) -> coalesced stores
        float (*so)[16][68] = sOut[ct & 1];
        *(float4v*)&so[0][lm][m0 + lq * 4] = (float4v){ob0[0], ob0[1], ob0[2], ob0[3]};
        *(float4v*)&so[1][lm][m0 + lq * 4] = (float4v){ob1[0], ob1[1], ob1[2], ob1[3]};
        __syncthreads();   // cross-lane handoff (R2 lesson: never skip)

        const int row = t >> 3;              // 0..31 = (b,ch16)
        const int b   = row >> 4, ch = row & 15;
        const int seg = (t & 7) * 8;
        float4v v0 = *(float4v*)&so[b][ch][seg];
        float4v v1 = *(float4v*)&so[b][ch][seg + 4];
        float* op = out + (((size_t)(b * CC + ct * 16 + ch) * HO) + y) * WO + x0 + seg;
        *(float4v*)op = v0;
        *(float4v*)(op + 4) = v1;
        // next ct writes the other sOut buffer -> no WAR barrier needed
    }
}

extern "C" void kernel_launch(void* const* d_in, const int* in_sizes, int n_in,
                              void* d_out, int out_size, void* d_ws, size_t ws_size,
                              hipStream_t stream) {
    const float* x    = (const float*)d_in[0];
    const float* pose = (const float*)d_in[1];
    const float* W1   = (const float*)d_in[2];
    const float* b1   = (const float*)d_in[3];
    const float* W2   = (const float*)d_in[4];
    const float* b2   = (const float*)d_in[5];
    const float* W3   = (const float*)d_in[6];
    const float* b3   = (const float*)d_in[7];
    const int*   iY   = (const int*)d_in[8];
    const int*   iX   = (const int*)d_in[9];
    float* out = (float*)d_out;
    unsigned short* wsp = (unsigned short*)d_ws;
    float* xt = (float*)((char*)d_ws + XT_ELEM_OFF * sizeof(unsigned short));

    prepack_zw<<<2048, NT, 0, stream>>>(W2, W3, wsp, xt);
    prepack_x<<<1024, NT, 0, stream>>>(x, xt);

    const int nblocks = (HO * WO) / NPX;   // 4096
    fused_main<<<nblocks, NT, 0, stream>>>(
        xt, pose, W1, b1, b2, b3, iY, iX, wsp, out);
}

// Round 3
// 521.180 us; speedup vs baseline: 1.2186x; 1.2186x over previous
//
#include <hip/hip_runtime.h>
#include <math.h>

// Problem constants
#define HO 512
#define WO 512
#define HI 128
#define WI 128
#define CC 64      // channels
#define BS 2       // batch
#define NPX 64     // pixels per block (one row segment)
#define NT 256     // threads per block

// d_ws layout:
//   [0)              bf16 packed weights: w2p then w3p
//   [XT_BYTE_OFF)    x_t padded transpose: float [130][130][2][64]
#define W2P_ELEMS (16 * 2 * 64 * 8)      // [nt=16][ks=2][lane=64][j=8]
#define W3P_ELEMS (36 * 8 * 64 * 8)      // [nt=36][ks=8][lane=64][j=8], nt = tap*4+chtile
#define XT_ELEM_OFF (W2P_ELEMS + W3P_ELEMS)     // in shorts (163840 -> 327680 B, 16B aligned)
#define XT_FLOATS (130 * 130 * 128)             // 2,163,200 floats = 8.65 MB

typedef __attribute__((ext_vector_type(8))) short short8;
typedef __attribute__((ext_vector_type(4))) float float4v;

__device__ __forceinline__ unsigned short f2bf(float f) {
    unsigned u = __builtin_bit_cast(unsigned, f);
    unsigned r = (u + 0x7FFFu + ((u >> 16) & 1u)) >> 16;   // RNE
    return (unsigned short)r;
}

// ---------------- k1: pack weights to MFMA-B order + zero x_t ----------------
// B-frag (16x16x32): lane l holds B[n=l&15][k=(l>>4)*8+j], j=0..7
// W3 n-tile nt = tap*4 + chtile: covers W3 rows (chtile*16 + (l&15))*9 + tap
__global__ void prepack_zw(const float* __restrict__ W2,
                           const float* __restrict__ W3,
                           unsigned short* __restrict__ wsp,
                           float* __restrict__ xt) {
    const int total = W2P_ELEMS + W3P_ELEMS;
    for (int idx = blockIdx.x * blockDim.x + threadIdx.x; idx < total;
         idx += gridDim.x * blockDim.x) {
        float v;
        if (idx < W2P_ELEMS) {
            int j = idx & 7, lane = (idx >> 3) & 63, rest = idx >> 9;
            int ks = rest & 1, nt = rest >> 1;
            int n = nt * 16 + (lane & 15);
            int k = ks * 32 + (lane >> 4) * 8 + j;
            v = W2[n * 64 + k];                      // W2: [256][64]
        } else {
            int i2 = idx - W2P_ELEMS;
            int j = i2 & 7, lane = (i2 >> 3) & 63, rest = i2 >> 9;
            int ks = rest & 7, nt = rest >> 3;       // nt = tap*4+chtile
            int tap = nt >> 2, ct = nt & 3;
            int row = (ct * 16 + (lane & 15)) * 9 + tap;   // < 576
            int k = ks * 32 + (lane >> 4) * 8 + j;
            v = W3[row * 256 + k];                   // W3: [576][256]
        }
        wsp[idx] = f2bf(v);
    }
    // zero x_t (borders stay zero; interior overwritten by prepack_x)
    float4v z = {0.f, 0.f, 0.f, 0.f};
    float4v* xt4 = (float4v*)xt;
    for (int i = blockIdx.x * blockDim.x + threadIdx.x; i < XT_FLOATS / 4;
         i += gridDim.x * blockDim.x)
        xt4[i] = z;
}

// ---------------- k2: x -> x_t[(h+1)][(w+1)][b][c] (interior) ----------------
// 262144 threads; lanes consecutive = consecutive w -> coalesced reads.
__global__ void prepack_x(const float* __restrict__ x, float* __restrict__ xt) {
    const int tid = blockIdx.x * blockDim.x + threadIdx.x;
    const int pos = tid & 16383;          // h*128+w
    const int g   = tid >> 14;            // bc group: 8 channels
    const int h = pos >> 7, w = pos & 127;
    const float* src = x + pos;
    float4v v0, v1;
    #pragma unroll
    for (int j = 0; j < 4; ++j) v0[j] = src[(size_t)(g * 8 + j) * (HI * WI)];
    #pragma unroll
    for (int j = 0; j < 4; ++j) v1[j] = src[(size_t)(g * 8 + 4 + j) * (HI * WI)];
    float* dst = xt + ((h + 1) * 130 + (w + 1)) * 128 + g * 8;
    *(float4v*)dst = v0;
    *(float4v*)(dst + 4) = v1;
}

// ---------------- fused main kernel ----------------
// Grid restructure vs the 303us version: the chtile loop is hoisted into the
// grid as the SLOWEST-varying block index (ct = blockIdx.x >> 12). All
// concurrently-resident blocks therefore gather from the SAME 16-channel
// slice of x_t: 130*130*(2*16ch*4B) = 2.16 MB, L2-resident per XCD (vs the
// full 8.65 MB that can't fit 4 MB L2 -> 589 MB of L2-miss traffic at L3
// latency). Stages 1+2 are recomputed per ct-pass (cheap MLP) to buy gather
// locality. Stage-3 inner code / LDS transpose / stores: identical to the
// proven 303us version (R1/R2 lesson: do NOT touch the softmax+gather
// schedule; the compiler's point-load interleave is the local optimum).
__global__ __launch_bounds__(NT, 3)
void fused_main(const float* __restrict__ xt, const float* __restrict__ pose,
                const float* __restrict__ W1, const float* __restrict__ b1,
                const float* __restrict__ b2, const float* __restrict__ b3,
                const int* __restrict__ iY, const int* __restrict__ iX,
                const unsigned short* __restrict__ wsp,
                float* __restrict__ out)
{
    // Manual LDS layout (44.3 KB -> 3 blocks/CU). sH1 dead after stage2;
    // overlap it with the (single-ct) sOut transpose tile.
    __shared__ char smem[33792 + 9216 + 768 + 512];
    unsigned short (*sH2)[264] = (unsigned short (*)[264])&smem[0];        // 33792 B
    unsigned short (*sH1)[72]  = (unsigned short (*)[72])&smem[33792];     // 9216 B (union)
    float (*sOut)[16][68]      = (float (*)[16][68])&smem[33792];          // 8704 B (union)
    float (*sP)[NPX]           = (float (*)[NPX])&smem[43008];             // 768 B
    int* sIY                   = (int*)&smem[43776];                       // 256 B
    int* sIX                   = (int*)&smem[44032];                       // 256 B

    const int t = threadIdx.x;
    const int ct  = blockIdx.x >> 12;        // chtile: slowest-varying
    const int blk = blockIdx.x & 4095;
    const int pixBase = blk * NPX;           // 64 px within one output row
    const int y  = pixBase / WO;
    const int x0 = pixBase % WO;

    if (t < 192) sP[t >> 6][t & 63] = pose[(t >> 6) * (HO * WO) + pixBase + (t & 63)];
    if (t < 64) sIY[t] = iY[pixBase + t];
    else if (t < 128) sIX[t - 64] = iX[pixBase + t - 64];
    __syncthreads();

    // ---- stage 1: h1 = relu(W1 @ p + b1)
    {
        const int p  = t & 63;
        const int og = t >> 6;
        const float p0 = sP[0][p], p1 = sP[1][p], p2 = sP[2][p];
        #pragma unroll
        for (int i = 0; i < 16; i += 2) {
            const int o = og * 16 + i;
            float a0 = fmaf(W1[o * 3 + 2], p2, fmaf(W1[o * 3 + 1], p1, fmaf(W1[o * 3 + 0], p0, b1[o])));
            float a1 = fmaf(W1[o * 3 + 5], p2, fmaf(W1[o * 3 + 4], p1, fmaf(W1[o * 3 + 3], p0, b1[o + 1])));
            a0 = fmaxf(a0, 0.f); a1 = fmaxf(a1, 0.f);
            unsigned pack = (unsigned)f2bf(a0) | ((unsigned)f2bf(a1) << 16);
            *(unsigned*)&sH1[p][o] = pack;
        }
    }
    __syncthreads();

    const int wv = t >> 6, l = t & 63, lm = l & 15, lq = l >> 4;
    const int m0 = wv * 16;                  // wave's pixel base

    // ---- stage 2: h2 = relu(h1 @ W2^T + b2)  [16px x 256] per wave
    {
        short8 a0 = *(const short8*)&sH1[m0 + lm][0  + lq * 8];
        short8 a1 = *(const short8*)&sH1[m0 + lm][32 + lq * 8];
        const short8* w2f = (const short8*)wsp;
        #pragma unroll 4
        for (int nt = 0; nt < 16; ++nt) {
            float4v acc = {0.f, 0.f, 0.f, 0.f};
            short8 bf0 = w2f[(nt * 2 + 0) * 64 + l];
            short8 bf1 = w2f[(nt * 2 + 1) * 64 + l];
            acc = __builtin_amdgcn_mfma_f32_16x16x32_bf16(a0, bf0, acc, 0, 0, 0);
            acc = __builtin_amdgcn_mfma_f32_16x16x32_bf16(a1, bf1, acc, 0, 0, 0);
            const float bv = b2[nt * 16 + lm];
            #pragma unroll
            for (int r = 0; r < 4; ++r)
                sH2[m0 + lq * 4 + r][nt * 16 + lm] = f2bf(fmaxf(acc[r] + bv, 0.f));
        }
    }
    __syncthreads();   // sH1 also dead beyond this point (sOut may overwrite)

    // per-lane pixel bases into x_t (pixels p = m0 + lq*4 + r)
    int pbase[4];
    #pragma unroll
    for (int r = 0; r < 4; ++r) {
        const int p = m0 + lq * 4 + r;
        pbase[r] = ((sIY[p] + 1) * 130 + (sIX[p] + 1)) * 128;
    }
    const int koff[9] = {-131 * 128, -130 * 128, -129 * 128,
                         -1 * 128,   0,          1 * 128,
                         129 * 128,  130 * 128,  131 * 128};
    const short8* w3f = (const short8*)(wsp + W2P_ELEMS);

    // ---- stage 3: THIS block's chtile (16 ch); 9 taps in registers
    {
        float4v accs[9];
        #pragma unroll
        for (int tap = 0; tap < 9; ++tap) accs[tap] = (float4v){0.f, 0.f, 0.f, 0.f};

        #pragma unroll 2
        for (int ks = 0; ks < 8; ++ks) {
            short8 a = *(const short8*)&sH2[m0 + lm][ks * 32 + lq * 8];
            #pragma unroll
            for (int tap = 0; tap < 9; ++tap) {
                short8 b = w3f[(((tap << 2) | ct) * 8 + ks) * 64 + l];
                accs[tap] = __builtin_amdgcn_mfma_f32_16x16x32_bf16(a, b, accs[tap], 0, 0, 0);
            }
        }

        const int c = ct * 16 + lm;          // this lane's channel
        float bv[9];
        #pragma unroll
        for (int tap = 0; tap < 9; ++tap) bv[tap] = b3[c * 9 + tap];

        float ob0[4], ob1[4];
        #pragma unroll
        for (int r = 0; r < 4; ++r) {
            float lg[9];
            #pragma unroll
            for (int tap = 0; tap < 9; ++tap) lg[tap] = accs[tap][r] + bv[tap];
            float mx = lg[0];
            #pragma unroll
            for (int tap = 1; tap < 9; ++tap) mx = fmaxf(mx, lg[tap]);
            const float* xb = xt + pbase[r] + c;
            float s = 0.f, o0 = 0.f, o1 = 0.f;
            #pragma unroll
            for (int tap = 0; tap < 9; ++tap) {
                const float ev = __expf(lg[tap] - mx);
                s += ev;
                o0 = fmaf(ev, xb[koff[tap]], o0);        // b=0, coalesced over lm
                o1 = fmaf(ev, xb[koff[tap] + 64], o1);   // b=1
            }
            const float inv = 1.f / s;
            ob0[r] = o0 * inv;
            ob1[r] = o1 * inv;
        }

        // transpose via LDS -> coalesced full-line stores
        *(float4v*)&sOut[0][lm][m0 + lq * 4] = (float4v){ob0[0], ob0[1], ob0[2], ob0[3]};
        *(float4v*)&sOut[1][lm][m0 + lq * 4] = (float4v){ob1[0], ob1[1], ob1[2], ob1[3]};
        __syncthreads();   // cross-lane handoff (R2 lesson: never skip)

        const int row = t >> 3;              // 0..31 = (b,ch16)
        const int b   = row >> 4, ch = row & 15;
        const int seg = (t & 7) * 8;
        float4v v0 = *(float4v*)&sOut[b][ch][seg];
        float4v v1 = *(float4v*)&sOut[b][ch][seg + 4];
        float* op = out + (((size_t)(b * CC + ct * 16 + ch) * HO) + y) * WO + x0 + seg;
        *(float4v*)op = v0;
        *(float4v*)(op + 4) = v1;
    }
}

extern "C" void kernel_launch(void* const* d_in, const int* in_sizes, int n_in,
                              void* d_out, int out_size, void* d_ws, size_t ws_size,
                              hipStream_t stream) {
    const float* x    = (const float*)d_in[0];
    const float* pose = (const float*)d_in[1];
    const float* W1   = (const float*)d_in[2];
    const float* b1   = (const float*)d_in[3];
    const float* W2   = (const float*)d_in[4];
    const float* b2   = (const float*)d_in[5];
    const float* W3   = (const float*)d_in[6];
    const float* b3   = (const float*)d_in[7];
    const int*   iY   = (const int*)d_in[8];
    const int*   iX   = (const int*)d_in[9];
    float* out = (float*)d_out;
    unsigned short* wsp = (unsigned short*)d_ws;
    float* xt = (float*)((char*)d_ws + XT_ELEM_OFF * sizeof(unsigned short));

    prepack_zw<<<2048, NT, 0, stream>>>(W2, W3, wsp, xt);
    prepack_x<<<1024, NT, 0, stream>>>(x, xt);

    const int nblocks = 4 * ((HO * WO) / NPX);   // 4 chtile passes x 4096 segments
    fused_main<<<nblocks, NT, 0, stream>>>(
        xt, pose, W1, b1, b2, b3, iY, iX, wsp, out);
}

// Round 4
// 395.587 us; speedup vs baseline: 1.6055x; 1.3175x over previous
//
#include <hip/hip_runtime.h>
#include <math.h>

// Problem constants
#define HO 512
#define WO 512
#define HI 128
#define WI 128
#define CC 64      // channels
#define BS 2       // batch
#define NPX 64     // pixels per block (one row segment)
#define NT 256     // threads per block

// d_ws layout:
//   [0)              bf16 packed weights: w2p then w3p
//   [XT_BYTE_OFF)    x_t padded transpose: float [130][130][64][2]  (c-major, b innermost)
#define W2P_ELEMS (16 * 2 * 64 * 8)      // [nt=16][ks=2][lane=64][j=8]
#define W3P_ELEMS (36 * 8 * 64 * 8)      // [nt=36][ks=8][lane=64][j=8], nt = tap*4+chtile
#define XT_ELEM_OFF (W2P_ELEMS + W3P_ELEMS)     // in shorts (163840 -> 327680 B, 16B aligned)
#define XT_FLOATS (130 * 130 * 128)             // 2,163,200 floats = 8.65 MB

typedef __attribute__((ext_vector_type(8))) short short8;
typedef __attribute__((ext_vector_type(4))) float float4v;
typedef __attribute__((ext_vector_type(2))) float float2v;

__device__ __forceinline__ unsigned short f2bf(float f) {
    unsigned u = __builtin_bit_cast(unsigned, f);
    unsigned r = (u + 0x7FFFu + ((u >> 16) & 1u)) >> 16;   // RNE
    return (unsigned short)r;
}

// ---------------- k1: pack weights to MFMA-B order + zero x_t ----------------
// B-frag (16x16x32): lane l holds B[n=l&15][k=(l>>4)*8+j], j=0..7
// W3 n-tile nt = tap*4 + chtile: covers W3 rows (chtile*16 + (l&15))*9 + tap
__global__ void prepack_zw(const float* __restrict__ W2,
                           const float* __restrict__ W3,
                           unsigned short* __restrict__ wsp,
                           float* __restrict__ xt) {
    const int total = W2P_ELEMS + W3P_ELEMS;
    for (int idx = blockIdx.x * blockDim.x + threadIdx.x; idx < total;
         idx += gridDim.x * blockDim.x) {
        float v;
        if (idx < W2P_ELEMS) {
            int j = idx & 7, lane = (idx >> 3) & 63, rest = idx >> 9;
            int ks = rest & 1, nt = rest >> 1;
            int n = nt * 16 + (lane & 15);
            int k = ks * 32 + (lane >> 4) * 8 + j;
            v = W2[n * 64 + k];                      // W2: [256][64]
        } else {
            int i2 = idx - W2P_ELEMS;
            int j = i2 & 7, lane = (i2 >> 3) & 63, rest = i2 >> 9;
            int ks = rest & 7, nt = rest >> 3;       // nt = tap*4+chtile
            int tap = nt >> 2, ct = nt & 3;
            int row = (ct * 16 + (lane & 15)) * 9 + tap;   // < 576
            int k = ks * 32 + (lane >> 4) * 8 + j;
            v = W3[row * 256 + k];                   // W3: [576][256]
        }
        wsp[idx] = f2bf(v);
    }
    // zero x_t (borders stay zero; interior overwritten by prepack_x)
    float4v z = {0.f, 0.f, 0.f, 0.f};
    float4v* xt4 = (float4v*)xt;
    for (int i = blockIdx.x * blockDim.x + threadIdx.x; i < XT_FLOATS / 4;
         i += gridDim.x * blockDim.x)
        xt4[i] = z;
}

// ---------------- k2: x -> x_t[(h+1)][(w+1)][c][b] (interior) ----------------
// 262144 threads; lanes consecutive = consecutive w -> coalesced reads.
// Batch innermost: each stage-3 tap gather becomes ONE float2 load (9 VMEM
// instructions per pixel-slot instead of 18), 128B contiguous per 16 lanes.
__global__ void prepack_x(const float* __restrict__ x, float* __restrict__ xt) {
    const int tid = blockIdx.x * blockDim.x + threadIdx.x;
    const int pos = tid & 16383;          // h*128+w
    const int g   = tid >> 14;            // channel group: 4 channels x 2 batches
    const int h = pos >> 7, w = pos & 127;
    const float* src = x + pos;
    float a0[4], a1[4];
    #pragma unroll
    for (int j = 0; j < 4; ++j) a0[j] = src[(size_t)(g * 4 + j) * (HI * WI)];            // b=0
    #pragma unroll
    for (int j = 0; j < 4; ++j) a1[j] = src[(size_t)(CC + g * 4 + j) * (HI * WI)];       // b=1
    float* dst = xt + ((h + 1) * 130 + (w + 1)) * 128 + g * 8;
    *(float4v*)dst       = (float4v){a0[0], a1[0], a0[1], a1[1]};
    *(float4v*)(dst + 4) = (float4v){a0[2], a1[2], a0[3], a1[3]};
}

// ---------------- fused main kernel ----------------
// Per block: 64 pixels (one row segment), 4 waves x 16 pixels. EXACT R0
// structure (ct loop inside, inline gathers in the softmax loop, LDS
// transpose + full-line stores). Single change vs the 303us version:
// x_t layout is [h][w][c][b] so each tap is one float2 load -> 144 gather
// instructions per thread instead of 288. R3 lesson: gather MISS latency is
// not the stall (L2-residency bought nothing) -> attack per-instruction
// issue/waitcnt cost instead. R1/R2 lesson: loads stay INLINE, no prefetch
// arrays, no schedule pinning.
__global__ __launch_bounds__(NT, 3)
void fused_main(const float* __restrict__ xt, const float* __restrict__ pose,
                const float* __restrict__ W1, const float* __restrict__ b1,
                const float* __restrict__ b2, const float* __restrict__ b3,
                const int* __restrict__ iY, const int* __restrict__ iX,
                const unsigned short* __restrict__ wsp,
                float* __restrict__ out)
{
    // Manual LDS layout (52.5 KB -> 3 blocks/CU). sH1 dead after stage2;
    // overlap it with the double-buffered sOut transpose tile.
    __shared__ char smem[33792 + 17408 + 768 + 512];
    unsigned short (*sH2)[264] = (unsigned short (*)[264])&smem[0];        // 33792 B
    unsigned short (*sH1)[72]  = (unsigned short (*)[72])&smem[33792];     // 9216 B (union)
    float (*sOut)[2][16][68]   = (float (*)[2][16][68])&smem[33792];       // 2x8704 B (union)
    float (*sP)[NPX]           = (float (*)[NPX])&smem[51200];             // 768 B
    int* sIY                   = (int*)&smem[51968];                       // 256 B
    int* sIX                   = (int*)&smem[52224];                       // 256 B

    const int t = threadIdx.x;
    const int pixBase = blockIdx.x * NPX;    // 64 px within one output row
    const int y  = pixBase / WO;
    const int x0 = pixBase % WO;

    if (t < 192) sP[t >> 6][t & 63] = pose[(t >> 6) * (HO * WO) + pixBase + (t & 63)];
    if (t < 64) sIY[t] = iY[pixBase + t];
    else if (t < 128) sIX[t - 64] = iX[pixBase + t - 64];
    __syncthreads();

    // ---- stage 1: h1 = relu(W1 @ p + b1)
    {
        const int p  = t & 63;
        const int og = t >> 6;
        const float p0 = sP[0][p], p1 = sP[1][p], p2 = sP[2][p];
        #pragma unroll
        for (int i = 0; i < 16; i += 2) {
            const int o = og * 16 + i;
            float a0 = fmaf(W1[o * 3 + 2], p2, fmaf(W1[o * 3 + 1], p1, fmaf(W1[o * 3 + 0], p0, b1[o])));
            float a1 = fmaf(W1[o * 3 + 5], p2, fmaf(W1[o * 3 + 4], p1, fmaf(W1[o * 3 + 3], p0, b1[o + 1])));
            a0 = fmaxf(a0, 0.f); a1 = fmaxf(a1, 0.f);
            unsigned pack = (unsigned)f2bf(a0) | ((unsigned)f2bf(a1) << 16);
            *(unsigned*)&sH1[p][o] = pack;
        }
    }
    __syncthreads();

    const int wv = t >> 6, l = t & 63, lm = l & 15, lq = l >> 4;
    const int m0 = wv * 16;                  // wave's pixel base

    // ---- stage 2: h2 = relu(h1 @ W2^T + b2)  [16px x 256] per wave
    {
        short8 a0 = *(const short8*)&sH1[m0 + lm][0  + lq * 8];
        short8 a1 = *(const short8*)&sH1[m0 + lm][32 + lq * 8];
        const short8* w2f = (const short8*)wsp;
        #pragma unroll 4
        for (int nt = 0; nt < 16; ++nt) {
            float4v acc = {0.f, 0.f, 0.f, 0.f};
            short8 bf0 = w2f[(nt * 2 + 0) * 64 + l];
            short8 bf1 = w2f[(nt * 2 + 1) * 64 + l];
            acc = __builtin_amdgcn_mfma_f32_16x16x32_bf16(a0, bf0, acc, 0, 0, 0);
            acc = __builtin_amdgcn_mfma_f32_16x16x32_bf16(a1, bf1, acc, 0, 0, 0);
            const float bv = b2[nt * 16 + lm];
            #pragma unroll
            for (int r = 0; r < 4; ++r)
                sH2[m0 + lq * 4 + r][nt * 16 + lm] = f2bf(fmaxf(acc[r] + bv, 0.f));
        }
    }
    __syncthreads();   // sH1 also dead beyond this point (sOut may overwrite)

    // per-lane pixel bases into x_t (pixels p = m0 + lq*4 + r)
    int pbase[4];
    #pragma unroll
    for (int r = 0; r < 4; ++r) {
        const int p = m0 + lq * 4 + r;
        pbase[r] = ((sIY[p] + 1) * 130 + (sIX[p] + 1)) * 128;
    }
    const int koff[9] = {-131 * 128, -130 * 128, -129 * 128,
                         -1 * 128,   0,          1 * 128,
                         129 * 128,  130 * 128,  131 * 128};
    const short8* w3f = (const short8*)(wsp + W2P_ELEMS);

    // ---- stage 3: 4 chtiles of 16 channels; 9 taps in registers
    for (int ct = 0; ct < 4; ++ct) {
        float4v accs[9];
        #pragma unroll
        for (int tap = 0; tap < 9; ++tap) accs[tap] = (float4v){0.f, 0.f, 0.f, 0.f};

        #pragma unroll 2
        for (int ks = 0; ks < 8; ++ks) {
            short8 a = *(const short8*)&sH2[m0 + lm][ks * 32 + lq * 8];
            #pragma unroll
            for (int tap = 0; tap < 9; ++tap) {
                short8 b = w3f[(((tap << 2) | ct) * 8 + ks) * 64 + l];
                accs[tap] = __builtin_amdgcn_mfma_f32_16x16x32_bf16(a, b, accs[tap], 0, 0, 0);
            }
        }

        const int c = ct * 16 + lm;          // this lane's channel
        float bv[9];
        #pragma unroll
        for (int tap = 0; tap < 9; ++tap) bv[tap] = b3[c * 9 + tap];

        float ob0[4], ob1[4];
        #pragma unroll
        for (int r = 0; r < 4; ++r) {
            float lg[9];
            #pragma unroll
            for (int tap = 0; tap < 9; ++tap) lg[tap] = accs[tap][r] + bv[tap];
            float mx = lg[0];
            #pragma unroll
            for (int tap = 1; tap < 9; ++tap) mx = fmaxf(mx, lg[tap]);
            const float* xb = xt + pbase[r] + 2 * c;
            float s = 0.f, o0 = 0.f, o1 = 0.f;
            #pragma unroll
            for (int tap = 0; tap < 9; ++tap) {
                const float ev = __expf(lg[tap] - mx);
                const float2v gg = *(const float2v*)(xb + koff[tap]);  // one 8B load: b=0,b=1
                s += ev;
                o0 = fmaf(ev, gg[0], o0);
                o1 = fmaf(ev, gg[1], o1);
            }
            const float inv = 1.f / s;
            ob0[r] = o0 * inv;
            ob1[r] = o1 * inv;
        }

        // transpose via LDS (double-buffered) -> coalesced stores
        float (*so)[16][68] = sOut[ct & 1];
        *(float4v*)&so[0][lm][m0 + lq * 4] = (float4v){ob0[0], ob0[1], ob0[2], ob0[3]};
        *(float4v*)&so[1][lm][m0 + lq * 4] = (float4v){ob1[0], ob1[1], ob1[2], ob1[3]};
        __syncthreads();   // cross-lane handoff (R2 lesson: never skip)

        const int row = t >> 3;              // 0..31 = (b,ch16)
        const int b   = row >> 4, ch = row & 15;
        const int seg = (t & 7) * 8;
        float4v v0 = *(float4v*)&so[b][ch][seg];
        float4v v1 = *(float4v*)&so[b][ch][seg + 4];
        float* op = out + (((size_t)(b * CC + ct * 16 + ch) * HO) + y) * WO + x0 + seg;
        *(float4v*)op = v0;
        *(float4v*)(op + 4) = v1;
        // next ct writes the other sOut buffer -> no WAR barrier needed
    }
}

extern "C" void kernel_launch(void* const* d_in, const int* in_sizes, int n_in,
                              void* d_out, int out_size, void* d_ws, size_t ws_size,
                              hipStream_t stream) {
    const float* x    = (const float*)d_in[0];
    const float* pose = (const float*)d_in[1];
    const float* W1   = (const float*)d_in[2];
    const float* b1   = (const float*)d_in[3];
    const float* W2   = (const float*)d_in[4];
    const float* b2   = (const float*)d_in[5];
    const float* W3   = (const float*)d_in[6];
    const float* b3   = (const float*)d_in[7];
    const int*   iY   = (const int*)d_in[8];
    const int*   iX   = (const int*)d_in[9];
    float* out = (float*)d_out;
    unsigned short* wsp = (unsigned short*)d_ws;
    float* xt = (float*)((char*)d_ws + XT_ELEM_OFF * sizeof(unsigned short));

    prepack_zw<<<2048, NT, 0, stream>>>(W2, W3, wsp, xt);
    prepack_x<<<1024, NT, 0, stream>>>(x, xt);

    const int nblocks = (HO * WO) / NPX;   // 4096
    fused_main<<<nblocks, NT, 0, stream>>>(
        xt, pose, W1, b1, b2, b3, iY, iX, wsp, out);
}